// Round 6
// baseline (13643.210 us; speedup 1.0000x reference)
//
#include <hip/hip_runtime.h>
#include <hip/hip_bf16.h>
#include <math.h>

// ---------------------------------------------------------------------------
// DeepAR forward — split-fp16 MFMA, round 6: PERSISTENT kernel.
// r5 post-mortem: 384 dependent dispatches x ~20us launch/drain overhead
// dominated (10.57ms total vs ~4us of real work per GEMM). This round runs
// all 128 steps in ONE kernel. Batch decomposes: 8 b-tile groups x 32 blocks
// sync via group-local flag barriers (no grid-wide sync until the final loss
// join). GEMM core is byte-identical to the verified r5 core.
// Predicted: 10.57ms -> 2.0-3.5ms, absmax unchanged (0.0039).
// ---------------------------------------------------------------------------

#define BB   512
#define TT   128
#define COV  4
#define EMB  64
#define HIDN 512
#define G4   2048
#define XLD  128            // padded x row: [prev, cov(4), emb(64), 0...]
#define K0TOT (XLD + HIDN)  // 640  (5 rounds of 128)
#define K12TOT (2*HIDN)     // 1024 (8 rounds of 128)
#define LOG2PI 1.8378770664093453f

typedef _Float16 f16x8 __attribute__((ext_vector_type(8)));
typedef float f32x16 __attribute__((ext_vector_type(16)));

__device__ __forceinline__ float sigmoidf_(float x) { return 1.0f / (1.0f + expf(-x)); }
__device__ __forceinline__ float softplusf_(float x) {
    return fmaxf(x, 0.0f) + log1pf(expf(-fabsf(x)));
}
__device__ __forceinline__ void split2(float v, _Float16* hi, _Float16* lo) {
    _Float16 h = (_Float16)v;
    *hi = h;
    *lo = (_Float16)(v - (float)h);
}

// ---------------------------------------------------------------------------
// Pack weights into hi/lo fp16 pairs, rows interleaved g' = j*4 + q.
// ---------------------------------------------------------------------------
__global__ __launch_bounds__(256) void pack_weights_split(
    const float* __restrict__ Wih0, const float* __restrict__ Whh0,
    const float* __restrict__ Wih1, const float* __restrict__ Whh1,
    const float* __restrict__ Wih2, const float* __restrict__ Whh2,
    const float* __restrict__ bih0, const float* __restrict__ bhh0,
    const float* __restrict__ bih1, const float* __restrict__ bhh1,
    const float* __restrict__ bih2, const float* __restrict__ bhh2,
    _Float16* __restrict__ W0h, _Float16* __restrict__ W0l,
    _Float16* __restrict__ W1h, _Float16* __restrict__ W1l,
    _Float16* __restrict__ W2h, _Float16* __restrict__ W2l,
    float* __restrict__ biasI)
{
    const int N0 = G4 * K0TOT;
    const int N1 = G4 * K12TOT;
    const int total = N0 + 2 * N1 + 3 * G4;
    for (int i = blockIdx.x * blockDim.x + threadIdx.x; i < total;
         i += gridDim.x * blockDim.x) {
        if (i < N0) {
            int gp = i / K0TOT, k = i - gp * K0TOT;
            int orig = ((gp & 3) << 9) + (gp >> 2);   // q*512 + j
            float v = 0.0f;
            if (k < 69)        v = Wih0[orig * 69 + k];
            else if (k >= XLD) v = Whh0[orig * HIDN + (k - XLD)];
            split2(v, &W0h[i], &W0l[i]);
        } else if (i < N0 + N1) {
            int m = i - N0;
            int gp = m >> 10, k = m & 1023;
            int orig = ((gp & 3) << 9) + (gp >> 2);
            float v = (k < HIDN) ? Wih1[orig * HIDN + k] : Whh1[orig * HIDN + (k - HIDN)];
            split2(v, &W1h[m], &W1l[m]);
        } else if (i < N0 + 2 * N1) {
            int m = i - N0 - N1;
            int gp = m >> 10, k = m & 1023;
            int orig = ((gp & 3) << 9) + (gp >> 2);
            float v = (k < HIDN) ? Wih2[orig * HIDN + k] : Whh2[orig * HIDN + (k - HIDN)];
            split2(v, &W2h[m], &W2l[m]);
        } else {
            int m = i - N0 - 2 * N1;
            int l = m >> 11, gp = m & 2047;
            int orig = ((gp & 3) << 9) + (gp >> 2);
            const float* bi = (l == 0) ? bih0 : ((l == 1) ? bih1 : bih2);
            const float* bh = (l == 0) ? bhh0 : ((l == 1) ? bhh1 : bhh2);
            biasI[m] = bi[orig] + bh[orig];
        }
    }
}

// ---------------------------------------------------------------------------
// State init: H hi/lo (6 planes each), C (3 f32), xdyn hi/lo, params,
// stepNll/stepObs, flags/donef/maskmode. Mask encoding autodetect.
// ---------------------------------------------------------------------------
__global__ __launch_bounds__(256) void init_state(
    const float* __restrict__ cov, const int* __restrict__ idx,
    const float* __restrict__ emb_table, const int* __restrict__ maskbuf,
    _Float16* __restrict__ Hh, _Float16* __restrict__ Hl,
    float* __restrict__ C, _Float16* __restrict__ xdh, _Float16* __restrict__ xdl,
    float* __restrict__ params, float* __restrict__ stepNll,
    float* __restrict__ stepObs,
    int* __restrict__ flags, int* __restrict__ donef, int* __restrict__ maskmode)
{
    const int PL = BB * HIDN;
    const int NH = 6 * PL;
    const int NC = 3 * PL;
    const int NX = BB * XLD;
    const int NFLT = 2 * BB + 2 * TT;         // params + stepNll + stepObs
    const int NINT = 8 * 32 + 8;              // flags + donef
    const int total = 2 * NH + NC + 2 * NX + NFLT + NINT;
    int gtid = blockIdx.x * blockDim.x + threadIdx.x;
    if (gtid == 0) {
        int w0 = maskbuf[0];
        *maskmode = (w0 == 0 || w0 == 1) ? 0 : 1;   // 0 = int32, 1 = bytes
    }
    for (int i = gtid; i < total; i += gridDim.x * blockDim.x) {
        if (i < NH)            Hh[i] = (_Float16)0.0f;
        else if (i < 2 * NH)   Hl[i - NH] = (_Float16)0.0f;
        else if (i < 2 * NH + NC) C[i - 2 * NH] = 0.0f;
        else if (i < 2 * NH + NC + 2 * NX) {
            int m = i - 2 * NH - NC;
            int isLo = (m >= NX); if (isLo) m -= NX;
            int b = m >> 7, k = m & 127;
            float v = 0.0f;
            if (k >= 1 && k < 1 + COV)      v = cov[(b * TT + 0) * COV + (k - 1)];
            else if (k >= 5 && k < 5 + EMB) v = emb_table[idx[b] * EMB + (k - 5)];
            _Float16 h = (_Float16)v;
            if (!isLo) xdh[m] = h;
            else       xdl[m] = (_Float16)(v - (float)h);
        } else if (i < 2 * NH + NC + 2 * NX + NFLT) {
            int m = i - 2 * NH - NC - 2 * NX;
            if (m < 2 * BB)          params[m] = 0.0f;
            else if (m < 2 * BB + TT) stepNll[m - 2 * BB] = 0.0f;
            else                      stepObs[m - 2 * BB - TT] = 0.0f;
        } else {
            int m = i - 2 * NH - NC - 2 * NX - NFLT;
            if (m < 256) flags[m] = 0;
            else         donef[m - 256] = 0;
        }
    }
}

// ---------------------------------------------------------------------------
// Group-local barrier: 32 blocks of one b-tile group. Flag-array arrive
// (one relaxed store per block) + 32-lane ballot spin. threadfence release
// before arrive (wbl2: publish h/xdyn to LLC), acquire after (inv stale L2).
// Generations are monotonic -> no reset races.
// ---------------------------------------------------------------------------
__device__ __forceinline__ void tile_barrier(int* gflags, int slot, int gen, int tid)
{
    __syncthreads();
    if (tid == 0) {
        __threadfence();   // release: write back dirty L2 before signaling
        __hip_atomic_store(&gflags[slot], gen, __ATOMIC_RELAXED,
                           __HIP_MEMORY_SCOPE_AGENT);
    }
    if (tid < 64) {
        int v;
        unsigned long long pend;
        do {
            __builtin_amdgcn_s_sleep(1);
            v = (tid < 32)
                ? __hip_atomic_load(&gflags[tid], __ATOMIC_RELAXED,
                                    __HIP_MEMORY_SCOPE_AGENT)
                : 0x7fffffff;
            pend = __ballot(v < gen);
        } while (pend != 0ull);
        __threadfence();   // acquire: invalidate stale clean lines
    }
    __syncthreads();
}

// ---------------------------------------------------------------------------
// One fused LSTM layer for this block's (b-tile, panel): GEMM (split-fp16,
// 3x mfma_f32_32x32x16_f16 per frag pair), LDS gate bounce, cell update,
// fc partials when isLast. Byte-identical math to the r5-verified core.
// ---------------------------------------------------------------------------
__device__ __forceinline__ void gemm_layer(
    _Float16* __restrict__ sm,
    const _Float16* __restrict__ A0h, const _Float16* __restrict__ A0l,
    int ldA0, int k0len,
    const _Float16* __restrict__ A1h, const _Float16* __restrict__ A1l,
    int ldA1, int kTot,
    const _Float16* __restrict__ Wh, const _Float16* __restrict__ Wl,
    const float* __restrict__ biasP,
    float* __restrict__ cPlane,
    _Float16* __restrict__ hOutH, _Float16* __restrict__ hOutL,
    int isLast, float* __restrict__ params, const float* __restrict__ fcw,
    int tid, int b0, int g, int g0)
{
    _Float16* Ahs = sm;
    _Float16* Als = sm + 8192;
    _Float16* Bhs = sm + 16384;
    _Float16* Bls = sm + 24576;
    float* gbuf = (float*)sm;                          // [64][68] alias

    const int lane = tid & 63;
    const int wv4  = (tid >> 6) & 3;
    const int kh   = tid >> 8;                // k-subtile group (0/1)
    const int wr   = wv4 >> 1;
    const int wc   = wv4 & 1;

    f32x16 acc = {0.0f};

    const int rA = (wr << 5) + (lane & 31);
    const int rB = (wc << 5) + (lane & 31);
    const int hi = lane >> 5;
    const int R  = kTot >> 7;                 // rounds of 128 k

    int srow[2], sc16[2], sdst[2];
    #pragma unroll
    for (int it = 0; it < 2; ++it) {
        int idx = (it << 9) + tid;            // 0..1023
        srow[it] = idx >> 4;
        sc16[it] = idx & 15;
        int sub = sc16[it] >> 3, c8 = sc16[it] & 7;
        sdst[it] = ((sub << 9) + (c8 << 6) + (srow[it] ^ c8)) << 3;
    }

    f16x8 pAh[2], pAl[2], pBh[2], pBl[2];

    // prefetch round 0
    #pragma unroll
    for (int it = 0; it < 2; ++it) {
        int k = sc16[it] << 3;
        const _Float16 *ph, *pl;
        if (k < k0len) {
            size_t off = (size_t)(b0 + srow[it]) * ldA0 + k;
            ph = A0h + off; pl = A0l + off;
        } else {
            size_t off = (size_t)(b0 + srow[it]) * ldA1 + (k - k0len);
            ph = A1h + off; pl = A1l + off;
        }
        pAh[it] = *(const f16x8*)ph;
        pAl[it] = *(const f16x8*)pl;
        size_t woff = (size_t)(g0 + srow[it]) * kTot + k;
        pBh[it] = *(const f16x8*)(Wh + woff);
        pBl[it] = *(const f16x8*)(Wl + woff);
    }

    for (int r = 0; r < R; ++r) {
        #pragma unroll
        for (int it = 0; it < 2; ++it) {
            *(f16x8*)(Ahs + sdst[it]) = pAh[it];
            *(f16x8*)(Als + sdst[it]) = pAl[it];
            *(f16x8*)(Bhs + sdst[it]) = pBh[it];
            *(f16x8*)(Bls + sdst[it]) = pBl[it];
        }
        __syncthreads();

        if (r + 1 < R) {
            int kt = (r + 1) << 7;
            #pragma unroll
            for (int it = 0; it < 2; ++it) {
                int k = kt + (sc16[it] << 3);
                const _Float16 *ph, *pl;
                if (k < k0len) {
                    size_t off = (size_t)(b0 + srow[it]) * ldA0 + k;
                    ph = A0h + off; pl = A0l + off;
                } else {
                    size_t off = (size_t)(b0 + srow[it]) * ldA1 + (k - k0len);
                    ph = A1h + off; pl = A1l + off;
                }
                pAh[it] = *(const f16x8*)ph;
                pAl[it] = *(const f16x8*)pl;
                size_t woff = (size_t)(g0 + srow[it]) * kTot + k;
                pBh[it] = *(const f16x8*)(Wh + woff);
                pBl[it] = *(const f16x8*)(Wl + woff);
            }
        }

        const int sbase = kh << 9;
        #pragma unroll
        for (int ks = 0; ks < 4; ++ks) {
            int ca = (ks << 1) + hi;
            int aIdx = ((sbase + (ca << 6) + (rA ^ ca))) << 3;
            int bIdx = ((sbase + (ca << 6) + (rB ^ ca))) << 3;
            f16x8 fah = *(const f16x8*)(Ahs + aIdx);
            f16x8 fal = *(const f16x8*)(Als + aIdx);
            f16x8 fbh = *(const f16x8*)(Bhs + bIdx);
            f16x8 fbl = *(const f16x8*)(Bls + bIdx);
            acc = __builtin_amdgcn_mfma_f32_32x32x16_f16(fal, fbh, acc, 0, 0, 0);
            acc = __builtin_amdgcn_mfma_f32_32x32x16_f16(fah, fbl, acc, 0, 0, 0);
            acc = __builtin_amdgcn_mfma_f32_32x32x16_f16(fah, fbh, acc, 0, 0, 0);
        }
        __syncthreads();
    }

    // combine split-K partials into gbuf
    {
        const int col = (wc << 5) + (lane & 31);
        const int rb  = (wr << 5) + (hi << 2);
        if (kh == 0) {
            #pragma unroll
            for (int r = 0; r < 16; ++r) {
                int row = rb + (r & 3) + ((r >> 2) << 3);
                gbuf[row * 68 + col] = acc[r];
            }
        }
        __syncthreads();
        if (kh == 1) {
            #pragma unroll
            for (int r = 0; r < 16; ++r) {
                int row = rb + (r & 3) + ((r >> 2) << 3);
                gbuf[row * 68 + col] += acc[r];
            }
        }
        __syncthreads();
    }

    // cell update
    {
        const int jl = tid & 15;
        const int bq = tid >> 4;                 // 0..31
        const int jg = (g << 4) + jl;
        const float4 bv = *(const float4*)&biasP[g0 + (jl << 2)];
        float f0 = 0.0f, f1 = 0.0f;
        if (isLast) { f0 = fcw[jg]; f1 = fcw[HIDN + jg]; }

        #pragma unroll
        for (int i = 0; i < 2; ++i) {
            const int b  = (bq << 1) + i;
            const int gb = b0 + b;
            const float4 gv = *(const float4*)&gbuf[b * 68 + (jl << 2)];
            float ig = sigmoidf_(gv.x + bv.x);
            float fg = sigmoidf_(gv.y + bv.y);
            float gg = tanhf(gv.z + bv.z);
            float og = sigmoidf_(gv.w + bv.w);
            float cold = cPlane[(size_t)gb * HIDN + jg];
            float cnew = fg * cold + ig * gg;
            float hnew = og * tanhf(cnew);
            cPlane[(size_t)gb * HIDN + jg] = cnew;
            split2(hnew, &hOutH[(size_t)gb * HIDN + jg], &hOutL[(size_t)gb * HIDN + jg]);
            if (isLast) {
                float v0 = hnew * f0, v1 = hnew * f1;
                #pragma unroll
                for (int off = 8; off > 0; off >>= 1) {
                    v0 += __shfl_down(v0, off, 16);
                    v1 += __shfl_down(v1, off, 16);
                }
                if (jl == 0) {
                    atomicAdd(&params[gb * 2 + 0], v0);
                    atomicAdd(&params[gb * 2 + 1], v1);
                }
            }
        }
    }
}

// ---------------------------------------------------------------------------
// Persistent kernel: 256 blocks (1/CU), all 128 steps. Block (bt,g) fixed.
// Per step: L0, bar, L1, bar, L2(+fc atomics), bar, sampler(g==0), bar.
// Final: per-group done flag; block 0 joins and computes the scalar loss.
// ---------------------------------------------------------------------------
__global__ __launch_bounds__(512, 1) void deepar_persist(
    const _Float16* __restrict__ W0h, const _Float16* __restrict__ W0l,
    const _Float16* __restrict__ W1h, const _Float16* __restrict__ W1l,
    const _Float16* __restrict__ W2h, const _Float16* __restrict__ W2l,
    const float* __restrict__ biasI,
    _Float16* __restrict__ Hh, _Float16* __restrict__ Hl,
    float* __restrict__ C,
    _Float16* __restrict__ xdh, _Float16* __restrict__ xdl,
    float* __restrict__ params, float* __restrict__ stepNll,
    float* __restrict__ stepObs,
    int* __restrict__ flags, int* __restrict__ donef,
    const int* __restrict__ maskmode,
    const float* __restrict__ target, const float* __restrict__ cov,
    const void* __restrict__ maskraw, const float* __restrict__ noise,
    const float* __restrict__ fcw, const float* __restrict__ fcb,
    float* __restrict__ out)
{
    __shared__ __align__(16) _Float16 sm[4 * 8192];   // 64 KiB

    const int tid = threadIdx.x;
    const int fid = blockIdx.x;
    const int g   = ((fid >> 6) << 3) | (fid & 7);   // panel 0..31 (g%8==fid%8)
    const int bt  = (fid >> 3) & 7;                  // b-tile group
    const int b0  = bt << 6;
    const int g0  = g << 6;
    int* gflags   = flags + bt * 32;

    const size_t PL = (size_t)BB * HIDN;
    const int mm = *maskmode;
    int gen = 0;

    for (int t = 0; t < TT; ++t) {
        const int pi = t & 1;
        const size_t curo = (pi ? 3 : 0) * PL;
        const size_t nxto = (pi ? 0 : 3) * PL;
        _Float16* H0ch = Hh + curo;        _Float16* H0cl = Hl + curo;
        _Float16* H1ch = H0ch + PL;        _Float16* H1cl = H0cl + PL;
        _Float16* H2ch = H1ch + PL;        _Float16* H2cl = H1cl + PL;
        _Float16* H0nh = Hh + nxto;        _Float16* H0nl = Hl + nxto;
        _Float16* H1nh = H0nh + PL;        _Float16* H1nl = H0nl + PL;
        _Float16* H2nh = H1nh + PL;        _Float16* H2nl = H1nl + PL;

        gemm_layer(sm, xdh, xdl, XLD, XLD, H0ch, H0cl, HIDN, K0TOT,
                   W0h, W0l, biasI, C, H0nh, H0nl,
                   0, params, fcw, tid, b0, g, g0);
        ++gen; tile_barrier(gflags, g, gen, tid);

        gemm_layer(sm, H0nh, H0nl, HIDN, HIDN, H1ch, H1cl, HIDN, K12TOT,
                   W1h, W1l, biasI + G4, C + PL, H1nh, H1nl,
                   0, params, fcw, tid, b0, g, g0);
        ++gen; tile_barrier(gflags, g, gen, tid);

        gemm_layer(sm, H1nh, H1nl, HIDN, HIDN, H2ch, H2cl, HIDN, K12TOT,
                   W2h, W2l, biasI + 2 * G4, C + 2 * PL, H2nh, H2nl,
                   1, params, fcw, tid, b0, g, g0);
        ++gen; tile_barrier(gflags, g, gen, tid);

        // ---- sampler: one block per group (panel 0)
        if (g == 0) {
            if (tid < 64) {
                const int b = b0 + tid;
                float mean  = params[b * 2 + 0] + fcb[0];
                float sigma = softplusf_(params[b * 2 + 1] + fcb[1]) + 1e-6f;
                out[1 + t * BB + b]           = mean;
                out[1 + TT * BB + t * BB + b] = sigma;
                float z = target[b * TT + t];
                float obs = mm
                    ? (((const unsigned char*)maskraw)[b * TT + t] ? 1.0f : 0.0f)
                    : (((const int*)maskraw)[b * TT + t] ? 1.0f : 0.0f);
                float nv = noise[t * BB + b];
                float dz = (z - mean) / sigma;
                float nll = 0.5f * LOG2PI + logf(sigma) + 0.5f * dz * dz;
                // atomic zeroing: params is an atomics-only object (no dirty
                // L2 lines vs the LLC-side atomicAdds next step)
                atomicExch(&params[b * 2 + 0], 0.0f);
                atomicExch(&params[b * 2 + 1], 0.0f);
                float sample = mean + sigma * nv;
                float nxt = (obs != 0.0f) ? z : sample;
                if (t + 1 < TT) split2(nxt, &xdh[b * XLD], &xdl[b * XLD]);
                float v0 = nll * obs, v1 = obs;
                #pragma unroll
                for (int off = 32; off > 0; off >>= 1) {
                    v0 += __shfl_down(v0, off);
                    v1 += __shfl_down(v1, off);
                }
                if (tid == 0) {
                    atomicAdd(&stepNll[t], v0);
                    atomicAdd(&stepObs[t], v1);
                }
            } else if (tid >= 256 && t + 1 < TT) {
                int m = tid - 256;               // 256 threads: 64 rows x 4 cov
                int r = b0 + (m >> 2), k = m & 3;
                split2(cov[(r * TT + (t + 1)) * COV + k],
                       &xdh[r * XLD + 1 + k], &xdl[r * XLD + 1 + k]);
            }
        }
        ++gen; tile_barrier(gflags, g, gen, tid);
    }

    // ---- group done; block 0 joins all groups and computes the loss
    if (g == 0 && tid == 0) {
        __threadfence();
        __hip_atomic_store(&donef[bt], 1, __ATOMIC_RELAXED,
                           __HIP_MEMORY_SCOPE_AGENT);
    }
    if (fid == 0) {
        if (tid < 64) {
            int v;
            unsigned long long pend;
            do {
                __builtin_amdgcn_s_sleep(2);
                v = (tid < 8)
                    ? __hip_atomic_load(&donef[tid], __ATOMIC_RELAXED,
                                        __HIP_MEMORY_SCOPE_AGENT)
                    : 1;
                pend = __ballot(v == 0);
            } while (pend != 0ull);
            __threadfence();
        }
        __syncthreads();
        if (tid == 0) {
            float total = 0.0f, cnt = 0.0f;
            for (int t = 0; t < TT; ++t) {
                float so = stepObs[t];
                float sl = (so > 0.0f) ? (stepNll[t] / fmaxf(so, 1.0f)) : 0.0f;
                total += sl;
                cnt += (so > 0.0f) ? 1.0f : 0.0f;
            }
            out[0] = (cnt > 0.0f) ? (total / cnt) : total;
        }
    }
}

// ---------------------------------------------------------------------------
extern "C" void kernel_launch(void* const* d_in, const int* in_sizes, int n_in,
                              void* d_out, int out_size, void* d_ws, size_t ws_size,
                              hipStream_t stream) {
    const float* target       = (const float*)d_in[0];
    const float* covariates   = (const float*)d_in[1];
    const void*  maskraw      = d_in[2];
    const int*   idx          = (const int*)d_in[3];
    const float* emb_table    = (const float*)d_in[4];
    const float* fc_w         = (const float*)d_in[5];
    const float* fc_b         = (const float*)d_in[6];
    const float* noise        = (const float*)d_in[7];
    const float* Wih0 = (const float*)d_in[8];
    const float* Whh0 = (const float*)d_in[9];
    const float* bih0 = (const float*)d_in[10];
    const float* bhh0 = (const float*)d_in[11];
    const float* Wih1 = (const float*)d_in[12];
    const float* Whh1 = (const float*)d_in[13];
    const float* bih1 = (const float*)d_in[14];
    const float* bhh1 = (const float*)d_in[15];
    const float* Wih2 = (const float*)d_in[16];
    const float* Whh2 = (const float*)d_in[17];
    const float* bih2 = (const float*)d_in[18];
    const float* bhh2 = (const float*)d_in[19];
    (void)in_sizes; (void)n_in; (void)ws_size;

    const size_t PLANE = (size_t)BB * HIDN;
    const size_t NW0 = (size_t)G4 * K0TOT;
    const size_t NW1 = (size_t)G4 * K12TOT;

    _Float16* p = (_Float16*)d_ws;
    _Float16* W0h = p; p += NW0;
    _Float16* W0l = p; p += NW0;
    _Float16* W1h = p; p += NW1;
    _Float16* W1l = p; p += NW1;
    _Float16* W2h = p; p += NW1;
    _Float16* W2l = p; p += NW1;
    _Float16* Hh  = p; p += 6 * PLANE;
    _Float16* Hl  = p; p += 6 * PLANE;
    _Float16* xdh = p; p += (size_t)BB * XLD;
    _Float16* xdl = p; p += (size_t)BB * XLD;
    float* fp = (float*)p;
    float* biasI   = fp; fp += 3 * G4;
    float* C       = fp; fp += 3 * PLANE;
    float* params  = fp; fp += 2 * BB;
    float* stepNll = fp; fp += TT;
    float* stepObs = fp; fp += TT;
    int* ip = (int*)fp;
    int* flags    = ip;      ip += 8 * 32;
    int* donef    = ip;      ip += 8;
    int* maskmode = ip;

    float* out = (float*)d_out; (void)out_size;

    pack_weights_split<<<1024, 256, 0, stream>>>(
        Wih0, Whh0, Wih1, Whh1, Wih2, Whh2,
        bih0, bhh0, bih1, bhh1, bih2, bhh2,
        W0h, W0l, W1h, W1l, W2h, W2l, biasI);
    init_state<<<1024, 256, 0, stream>>>(
        covariates, idx, emb_table, (const int*)maskraw,
        Hh, Hl, C, xdh, xdl, params, stepNll, stepObs,
        flags, donef, maskmode);

    deepar_persist<<<256, 512, 0, stream>>>(
        W0h, W0l, W1h, W1l, W2h, W2l, biasI,
        Hh, Hl, C, xdh, xdl, params, stepNll, stepObs,
        flags, donef, maskmode,
        target, covariates, maskraw, noise, fc_w, fc_b, out);
}

// Round 10
// 5118.647 us; speedup vs baseline: 2.6654x; 2.6654x over previous
//
#include <hip/hip_runtime.h>
#include <hip/hip_bf16.h>
#include <math.h>

// ---------------------------------------------------------------------------
// DeepAR forward — split-fp16 MFMA, round 10 (= round 7 kernel, fourth
// submit; r7/r8/r9 never ran: GPU acquisition timeouts). r6 post-mortem
// (counters): MfmaUtil 6.3%, VALUBusy 3.7% -> latency-bound; __threadfence()
// in the group barrier = agent release/acquire = full L2 writeback+invalidate
// per barrier -> 11.1 GB/run of cold W/A re-fetch.
// This kernel: payload-only coherence. h/xdyn exchanged via sc0|sc1
// write-through stores + sc0|sc1 direct-to-LLC loads (issued early,
// vmcnt-waited late, hidden under MFMA). W/bias/C stay normally cached ->
// L2-resident all run. Barrier keeps the proven flag/gen protocol, drops
// ALL threadfences. GEMM math & structure byte-identical to the verified
// r5/r6 core. Predicted: 13.64 ms -> 2.5-4.5 ms, absmax unchanged (0.0039).
// ---------------------------------------------------------------------------

#define BB   512
#define TT   128
#define COV  4
#define EMB  64
#define HIDN 512
#define G4   2048
#define XLD  128            // padded x row: [prev, cov(4), emb(64), 0...]
#define K0TOT (XLD + HIDN)  // 640  (5 rounds of 128)
#define K12TOT (2*HIDN)     // 1024 (8 rounds of 128)
#define LOG2PI 1.8378770664093453f

typedef _Float16 f16x8 __attribute__((ext_vector_type(8)));
typedef float f32x16 __attribute__((ext_vector_type(16)));

__device__ __forceinline__ float sigmoidf_(float x) { return 1.0f / (1.0f + expf(-x)); }
__device__ __forceinline__ float softplusf_(float x) {
    return fmaxf(x, 0.0f) + log1pf(expf(-fabsf(x)));
}
__device__ __forceinline__ void split2(float v, _Float16* hi, _Float16* lo) {
    _Float16 h = (_Float16)v;
    *hi = h;
    *lo = (_Float16)(v - (float)h);
}

// ---- coherent (sc0|sc1) payload primitives -------------------------------
// store: write-through to coherence point (no cache-wide writeback needed)
__device__ __forceinline__ void store_coh_f16(_Float16* p, _Float16 v) {
    unsigned int w = (unsigned int)__builtin_bit_cast(unsigned short, v);
    asm volatile("global_store_short %0, %1, off sc0 sc1"
                 :: "v"(p), "v"(w) : "memory");
}
__device__ __forceinline__ void split2_coh(float v, _Float16* ph, _Float16* pl) {
    _Float16 h = (_Float16)v;
    _Float16 l = (_Float16)(v - (float)h);
    store_coh_f16(ph, h);
    store_coh_f16(pl, l);
}
// issue a 16B coherent load; result valid only after WAIT_VM0()
#define ISSUE_COH16(dst, ptr)                                              \
    asm volatile("global_load_dwordx4 %0, %1, off sc0 sc1"                 \
                 : "=&v"(dst) : "v"(ptr) : "memory")
#define WAIT_VM0()                                                         \
    do { asm volatile("s_waitcnt vmcnt(0)" ::: "memory");                  \
         __builtin_amdgcn_sched_barrier(0); } while (0)

// ---------------------------------------------------------------------------
// Pack weights into hi/lo fp16 pairs, rows interleaved g' = j*4 + q.
// ---------------------------------------------------------------------------
__global__ __launch_bounds__(256) void pack_weights_split(
    const float* __restrict__ Wih0, const float* __restrict__ Whh0,
    const float* __restrict__ Wih1, const float* __restrict__ Whh1,
    const float* __restrict__ Wih2, const float* __restrict__ Whh2,
    const float* __restrict__ bih0, const float* __restrict__ bhh0,
    const float* __restrict__ bih1, const float* __restrict__ bhh1,
    const float* __restrict__ bih2, const float* __restrict__ bhh2,
    _Float16* __restrict__ W0h, _Float16* __restrict__ W0l,
    _Float16* __restrict__ W1h, _Float16* __restrict__ W1l,
    _Float16* __restrict__ W2h, _Float16* __restrict__ W2l,
    float* __restrict__ biasI)
{
    const int N0 = G4 * K0TOT;
    const int N1 = G4 * K12TOT;
    const int total = N0 + 2 * N1 + 3 * G4;
    for (int i = blockIdx.x * blockDim.x + threadIdx.x; i < total;
         i += gridDim.x * blockDim.x) {
        if (i < N0) {
            int gp = i / K0TOT, k = i - gp * K0TOT;
            int orig = ((gp & 3) << 9) + (gp >> 2);   // q*512 + j
            float v = 0.0f;
            if (k < 69)        v = Wih0[orig * 69 + k];
            else if (k >= XLD) v = Whh0[orig * HIDN + (k - XLD)];
            split2(v, &W0h[i], &W0l[i]);
        } else if (i < N0 + N1) {
            int m = i - N0;
            int gp = m >> 10, k = m & 1023;
            int orig = ((gp & 3) << 9) + (gp >> 2);
            float v = (k < HIDN) ? Wih1[orig * HIDN + k] : Whh1[orig * HIDN + (k - HIDN)];
            split2(v, &W1h[m], &W1l[m]);
        } else if (i < N0 + 2 * N1) {
            int m = i - N0 - N1;
            int gp = m >> 10, k = m & 1023;
            int orig = ((gp & 3) << 9) + (gp >> 2);
            float v = (k < HIDN) ? Wih2[orig * HIDN + k] : Whh2[orig * HIDN + (k - HIDN)];
            split2(v, &W2h[m], &W2l[m]);
        } else {
            int m = i - N0 - 2 * N1;
            int l = m >> 11, gp = m & 2047;
            int orig = ((gp & 3) << 9) + (gp >> 2);
            const float* bi = (l == 0) ? bih0 : ((l == 1) ? bih1 : bih2);
            const float* bh = (l == 0) ? bhh0 : ((l == 1) ? bhh1 : bhh2);
            biasI[m] = bi[orig] + bh[orig];
        }
    }
}

// ---------------------------------------------------------------------------
// State init: H hi/lo, C, xdyn hi/lo, params, stepNll/stepObs, flags/donef,
// maskmode (int32 vs byte bools autodetect).
// ---------------------------------------------------------------------------
__global__ __launch_bounds__(256) void init_state(
    const float* __restrict__ cov, const int* __restrict__ idx,
    const float* __restrict__ emb_table, const int* __restrict__ maskbuf,
    _Float16* __restrict__ Hh, _Float16* __restrict__ Hl,
    float* __restrict__ C, _Float16* __restrict__ xdh, _Float16* __restrict__ xdl,
    float* __restrict__ params, float* __restrict__ stepNll,
    float* __restrict__ stepObs,
    int* __restrict__ flags, int* __restrict__ donef, int* __restrict__ maskmode)
{
    const int PL = BB * HIDN;
    const int NH = 6 * PL;
    const int NC = 3 * PL;
    const int NX = BB * XLD;
    const int NFLT = 2 * BB + 2 * TT;
    const int NINT = 8 * 32 + 8;
    const int total = 2 * NH + NC + 2 * NX + NFLT + NINT;
    int gtid = blockIdx.x * blockDim.x + threadIdx.x;
    if (gtid == 0) {
        int w0 = maskbuf[0];
        *maskmode = (w0 == 0 || w0 == 1) ? 0 : 1;
    }
    for (int i = gtid; i < total; i += gridDim.x * blockDim.x) {
        if (i < NH)            Hh[i] = (_Float16)0.0f;
        else if (i < 2 * NH)   Hl[i - NH] = (_Float16)0.0f;
        else if (i < 2 * NH + NC) C[i - 2 * NH] = 0.0f;
        else if (i < 2 * NH + NC + 2 * NX) {
            int m = i - 2 * NH - NC;
            int isLo = (m >= NX); if (isLo) m -= NX;
            int b = m >> 7, k = m & 127;
            float v = 0.0f;
            if (k >= 1 && k < 1 + COV)      v = cov[(b * TT + 0) * COV + (k - 1)];
            else if (k >= 5 && k < 5 + EMB) v = emb_table[idx[b] * EMB + (k - 5)];
            _Float16 h = (_Float16)v;
            if (!isLo) xdh[m] = h;
            else       xdl[m] = (_Float16)(v - (float)h);
        } else if (i < 2 * NH + NC + 2 * NX + NFLT) {
            int m = i - 2 * NH - NC - 2 * NX;
            if (m < 2 * BB)           params[m] = 0.0f;
            else if (m < 2 * BB + TT) stepNll[m - 2 * BB] = 0.0f;
            else                      stepObs[m - 2 * BB - TT] = 0.0f;
        } else {
            int m = i - 2 * NH - NC - 2 * NX - NFLT;
            if (m < 256) flags[m] = 0;
            else         donef[m - 256] = 0;
        }
    }
}

// ---------------------------------------------------------------------------
// Group barrier, FENCE-FREE: payload is coherent by construction (sc-bit
// accesses / HW atomics), so no cache-wide fences. vmcnt drain orders all
// payload (stores AND atomics) before the flag store. Monotonic generations.
// ---------------------------------------------------------------------------
__device__ __forceinline__ void tile_barrier(int* gflags, int slot, int gen, int tid)
{
    asm volatile("s_waitcnt vmcnt(0) lgkmcnt(0)" ::: "memory");
    __syncthreads();
    if (tid == 0) {
        __hip_atomic_store(&gflags[slot], gen, __ATOMIC_RELAXED,
                           __HIP_MEMORY_SCOPE_AGENT);
    }
    if (tid < 64) {
        int v;
        unsigned long long pend;
        do {
            __builtin_amdgcn_s_sleep(1);
            v = (tid < 32)
                ? __hip_atomic_load(&gflags[tid], __ATOMIC_RELAXED,
                                    __HIP_MEMORY_SCOPE_AGENT)
                : 0x7fffffff;
            pend = __ballot(v < gen);
        } while (pend != 0ull);
    }
    __syncthreads();
    __builtin_amdgcn_sched_barrier(0);
}

// ---------------------------------------------------------------------------
// Issue the two coherent 16B A-loads (hi,lo) for one staged chunk.
// ---------------------------------------------------------------------------
__device__ __forceinline__ void issue_A(
    const _Float16* __restrict__ A0h, const _Float16* __restrict__ A0l,
    int ldA0, int k0len,
    const _Float16* __restrict__ A1h, const _Float16* __restrict__ A1l,
    int ldA1, int b0, int row, int k, f16x8* dh, f16x8* dl)
{
    const _Float16 *ph, *pl;
    if (k < k0len) {
        size_t off = (size_t)(b0 + row) * ldA0 + k;
        ph = A0h + off; pl = A0l + off;
    } else {
        size_t off = (size_t)(b0 + row) * ldA1 + (k - k0len);
        ph = A1h + off; pl = A1l + off;
    }
    ISSUE_COH16(*dh, ph);
    ISSUE_COH16(*dl, pl);
}

// ---------------------------------------------------------------------------
// One fused LSTM layer (b-tile, panel): split-fp16 GEMM + LDS gate bounce +
// cell update (+ fc partials when isLast). A-operand via coherent loads
// (issued early, waited at next round's LDS write). W via normal cached
// loads (L2-resident). h outputs via coherent write-through stores.
// ---------------------------------------------------------------------------
__device__ __forceinline__ void gemm_layer(
    _Float16* __restrict__ sm,
    const _Float16* __restrict__ A0h, const _Float16* __restrict__ A0l,
    int ldA0, int k0len,
    const _Float16* __restrict__ A1h, const _Float16* __restrict__ A1l,
    int ldA1, int kTot,
    const _Float16* __restrict__ Wh, const _Float16* __restrict__ Wl,
    const float* __restrict__ biasP,
    float* __restrict__ cPlane,
    _Float16* __restrict__ hOutH, _Float16* __restrict__ hOutL,
    int isLast, float* __restrict__ params, const float* __restrict__ fcw,
    int tid, int b0, int g, int g0)
{
    _Float16* Ahs = sm;
    _Float16* Als = sm + 8192;
    _Float16* Bhs = sm + 16384;
    _Float16* Bls = sm + 24576;
    float* gbuf = (float*)sm;                          // [64][68] alias

    const int lane = tid & 63;
    const int wv4  = (tid >> 6) & 3;
    const int kh   = tid >> 8;                // k-subtile group (0/1)
    const int wr   = wv4 >> 1;
    const int wc   = wv4 & 1;

    f32x16 acc = {0.0f};

    const int rA = (wr << 5) + (lane & 31);
    const int rB = (wc << 5) + (lane & 31);
    const int hi = lane >> 5;
    const int R  = kTot >> 7;                 // rounds of 128 k

    int srow[2], sc16[2], sdst[2];
    #pragma unroll
    for (int it = 0; it < 2; ++it) {
        int idx = (it << 9) + tid;            // 0..1023
        srow[it] = idx >> 4;
        sc16[it] = idx & 15;
        int sub = sc16[it] >> 3, c8 = sc16[it] & 7;
        sdst[it] = ((sub << 9) + (c8 << 6) + (srow[it] ^ c8)) << 3;
    }

    f16x8 pAh0, pAl0, pAh1, pAl1, pBh0, pBl0, pBh1, pBl1;

    // prefetch round 0 (A coherent-issued; W normal cached)
    issue_A(A0h, A0l, ldA0, k0len, A1h, A1l, ldA1, b0,
            srow[0], sc16[0] << 3, &pAh0, &pAl0);
    issue_A(A0h, A0l, ldA0, k0len, A1h, A1l, ldA1, b0,
            srow[1], sc16[1] << 3, &pAh1, &pAl1);
    {
        size_t w0 = (size_t)(g0 + srow[0]) * kTot + (sc16[0] << 3);
        size_t w1 = (size_t)(g0 + srow[1]) * kTot + (sc16[1] << 3);
        pBh0 = *(const f16x8*)(Wh + w0);  pBl0 = *(const f16x8*)(Wl + w0);
        pBh1 = *(const f16x8*)(Wh + w1);  pBl1 = *(const f16x8*)(Wl + w1);
    }

    for (int r = 0; r < R; ++r) {
        WAIT_VM0();                            // A-issues (and W) complete
        *(f16x8*)(Ahs + sdst[0]) = pAh0;
        *(f16x8*)(Als + sdst[0]) = pAl0;
        *(f16x8*)(Bhs + sdst[0]) = pBh0;
        *(f16x8*)(Bls + sdst[0]) = pBl0;
        *(f16x8*)(Ahs + sdst[1]) = pAh1;
        *(f16x8*)(Als + sdst[1]) = pAl1;
        *(f16x8*)(Bhs + sdst[1]) = pBh1;
        *(f16x8*)(Bls + sdst[1]) = pBl1;
        __syncthreads();

        if (r + 1 < R) {                       // issue next round (hides
            int kt = (r + 1) << 7;             //  under the MFMAs below)
            issue_A(A0h, A0l, ldA0, k0len, A1h, A1l, ldA1, b0,
                    srow[0], kt + (sc16[0] << 3), &pAh0, &pAl0);
            issue_A(A0h, A0l, ldA0, k0len, A1h, A1l, ldA1, b0,
                    srow[1], kt + (sc16[1] << 3), &pAh1, &pAl1);
            size_t w0 = (size_t)(g0 + srow[0]) * kTot + kt + (sc16[0] << 3);
            size_t w1 = (size_t)(g0 + srow[1]) * kTot + kt + (sc16[1] << 3);
            pBh0 = *(const f16x8*)(Wh + w0);  pBl0 = *(const f16x8*)(Wl + w0);
            pBh1 = *(const f16x8*)(Wh + w1);  pBl1 = *(const f16x8*)(Wl + w1);
        }

        const int sbase = kh << 9;
        #pragma unroll
        for (int ks = 0; ks < 4; ++ks) {
            int ca = (ks << 1) + hi;
            int aIdx = ((sbase + (ca << 6) + (rA ^ ca))) << 3;
            int bIdx = ((sbase + (ca << 6) + (rB ^ ca))) << 3;
            f16x8 fah = *(const f16x8*)(Ahs + aIdx);
            f16x8 fal = *(const f16x8*)(Als + aIdx);
            f16x8 fbh = *(const f16x8*)(Bhs + bIdx);
            f16x8 fbl = *(const f16x8*)(Bls + bIdx);
            acc = __builtin_amdgcn_mfma_f32_32x32x16_f16(fal, fbh, acc, 0, 0, 0);
            acc = __builtin_amdgcn_mfma_f32_32x32x16_f16(fah, fbl, acc, 0, 0, 0);
            acc = __builtin_amdgcn_mfma_f32_32x32x16_f16(fah, fbh, acc, 0, 0, 0);
        }
        __syncthreads();
    }

    // combine split-K partials into gbuf
    {
        const int col = (wc << 5) + (lane & 31);
        const int rb  = (wr << 5) + (hi << 2);
        if (kh == 0) {
            #pragma unroll
            for (int r = 0; r < 16; ++r) {
                int row = rb + (r & 3) + ((r >> 2) << 3);
                gbuf[row * 68 + col] = acc[r];
            }
        }
        __syncthreads();
        if (kh == 1) {
            #pragma unroll
            for (int r = 0; r < 16; ++r) {
                int row = rb + (r & 3) + ((r >> 2) << 3);
                gbuf[row * 68 + col] += acc[r];
            }
        }
        __syncthreads();
    }

    // cell update
    {
        const int jl = tid & 15;
        const int bq = tid >> 4;                 // 0..31
        const int jg = (g << 4) + jl;
        const float4 bv = *(const float4*)&biasP[g0 + (jl << 2)];
        float f0 = 0.0f, f1 = 0.0f;
        if (isLast) { f0 = fcw[jg]; f1 = fcw[HIDN + jg]; }

        #pragma unroll
        for (int i = 0; i < 2; ++i) {
            const int b  = (bq << 1) + i;
            const int gb = b0 + b;
            const float4 gv = *(const float4*)&gbuf[b * 68 + (jl << 2)];
            float ig = sigmoidf_(gv.x + bv.x);
            float fg = sigmoidf_(gv.y + bv.y);
            float gg = tanhf(gv.z + bv.z);
            float og = sigmoidf_(gv.w + bv.w);
            float cold = cPlane[(size_t)gb * HIDN + jg];    // block-private
            float cnew = fg * cold + ig * gg;
            float hnew = og * tanhf(cnew);
            cPlane[(size_t)gb * HIDN + jg] = cnew;
            split2_coh(hnew, &hOutH[(size_t)gb * HIDN + jg],
                             &hOutL[(size_t)gb * HIDN + jg]);
            if (isLast) {
                float v0 = hnew * f0, v1 = hnew * f1;
                #pragma unroll
                for (int off = 8; off > 0; off >>= 1) {
                    v0 += __shfl_down(v0, off, 16);
                    v1 += __shfl_down(v1, off, 16);
                }
                if (jl == 0) {
                    atomicAdd(&params[gb * 2 + 0], v0);
                    atomicAdd(&params[gb * 2 + 1], v1);
                }
            }
        }
    }
}

// ---------------------------------------------------------------------------
// Persistent kernel: 256 blocks (1/CU), all 128 steps. Block (bt,g) fixed.
// Per step: L0, bar, L1, bar, L2(+fc atomics), bar, sampler(g==0), bar.
// ---------------------------------------------------------------------------
__global__ __launch_bounds__(512, 1) void deepar_persist(
    const _Float16* __restrict__ W0h, const _Float16* __restrict__ W0l,
    const _Float16* __restrict__ W1h, const _Float16* __restrict__ W1l,
    const _Float16* __restrict__ W2h, const _Float16* __restrict__ W2l,
    const float* __restrict__ biasI,
    _Float16* __restrict__ Hh, _Float16* __restrict__ Hl,
    float* __restrict__ C,
    _Float16* __restrict__ xdh, _Float16* __restrict__ xdl,
    float* __restrict__ params, float* __restrict__ stepNll,
    float* __restrict__ stepObs,
    int* __restrict__ flags, int* __restrict__ donef,
    const int* __restrict__ maskmode,
    const float* __restrict__ target, const float* __restrict__ cov,
    const void* __restrict__ maskraw, const float* __restrict__ noise,
    const float* __restrict__ fcw, const float* __restrict__ fcb,
    float* __restrict__ out)
{
    __shared__ __align__(16) _Float16 sm[4 * 8192];   // 64 KiB

    const int tid = threadIdx.x;
    const int fid = blockIdx.x;
    const int g   = ((fid >> 6) << 3) | (fid & 7);   // panel 0..31 (g%8==fid%8)
    const int bt  = (fid >> 3) & 7;                  // b-tile group
    const int b0  = bt << 6;
    const int g0  = g << 6;
    int* gflags   = flags + bt * 32;

    const size_t PL = (size_t)BB * HIDN;
    const int mm = *maskmode;
    int gen = 0;

    for (int t = 0; t < TT; ++t) {
        const int pi = t & 1;
        const size_t curo = (pi ? 3 : 0) * PL;
        const size_t nxto = (pi ? 0 : 3) * PL;
        _Float16* H0ch = Hh + curo;        _Float16* H0cl = Hl + curo;
        _Float16* H1ch = H0ch + PL;        _Float16* H1cl = H0cl + PL;
        _Float16* H2ch = H1ch + PL;        _Float16* H2cl = H1cl + PL;
        _Float16* H0nh = Hh + nxto;        _Float16* H0nl = Hl + nxto;
        _Float16* H1nh = H0nh + PL;        _Float16* H1nl = H0nl + PL;
        _Float16* H2nh = H1nh + PL;        _Float16* H2nl = H1nl + PL;

        gemm_layer(sm, xdh, xdl, XLD, XLD, H0ch, H0cl, HIDN, K0TOT,
                   W0h, W0l, biasI, C, H0nh, H0nl,
                   0, params, fcw, tid, b0, g, g0);
        ++gen; tile_barrier(gflags, g, gen, tid);

        gemm_layer(sm, H0nh, H0nl, HIDN, HIDN, H1ch, H1cl, HIDN, K12TOT,
                   W1h, W1l, biasI + G4, C + PL, H1nh, H1nl,
                   0, params, fcw, tid, b0, g, g0);
        ++gen; tile_barrier(gflags, g, gen, tid);

        gemm_layer(sm, H1nh, H1nl, HIDN, HIDN, H2ch, H2cl, HIDN, K12TOT,
                   W2h, W2l, biasI + 2 * G4, C + 2 * PL, H2nh, H2nl,
                   1, params, fcw, tid, b0, g, g0);
        ++gen; tile_barrier(gflags, g, gen, tid);

        // ---- sampler: one block per group (panel 0)
        if (g == 0) {
            if (tid < 64) {
                const int b = b0 + tid;
                float p0 = __hip_atomic_load(&params[b * 2 + 0], __ATOMIC_RELAXED,
                                             __HIP_MEMORY_SCOPE_AGENT);
                float p1 = __hip_atomic_load(&params[b * 2 + 1], __ATOMIC_RELAXED,
                                             __HIP_MEMORY_SCOPE_AGENT);
                float mean  = p0 + fcb[0];
                float sigma = softplusf_(p1 + fcb[1]) + 1e-6f;
                out[1 + t * BB + b]           = mean;
                out[1 + TT * BB + t * BB + b] = sigma;
                float z = target[b * TT + t];
                float obs = mm
                    ? (((const unsigned char*)maskraw)[b * TT + t] ? 1.0f : 0.0f)
                    : (((const int*)maskraw)[b * TT + t] ? 1.0f : 0.0f);
                float nv = noise[t * BB + b];
                float dz = (z - mean) / sigma;
                float nll = 0.5f * LOG2PI + logf(sigma) + 0.5f * dz * dz;
                atomicExch(&params[b * 2 + 0], 0.0f);
                atomicExch(&params[b * 2 + 1], 0.0f);
                float sample = mean + sigma * nv;
                float nxt = (obs != 0.0f) ? z : sample;
                if (t + 1 < TT) split2_coh(nxt, &xdh[b * XLD], &xdl[b * XLD]);
                float v0 = nll * obs, v1 = obs;
                #pragma unroll
                for (int off = 32; off > 0; off >>= 1) {
                    v0 += __shfl_down(v0, off);
                    v1 += __shfl_down(v1, off);
                }
                if (tid == 0) {
                    atomicAdd(&stepNll[t], v0);
                    atomicAdd(&stepObs[t], v1);
                }
            } else if (tid >= 256 && t + 1 < TT) {
                int m = tid - 256;               // 256 threads: 64 rows x 4 cov
                int r = b0 + (m >> 2), k = m & 3;
                split2_coh(cov[(r * TT + (t + 1)) * COV + k],
                           &xdh[r * XLD + 1 + k], &xdl[r * XLD + 1 + k]);
            }
        }
        ++gen; tile_barrier(gflags, g, gen, tid);
    }

    // ---- group done; block 0 joins all groups and computes the loss
    if (g == 0 && tid == 0) {
        __hip_atomic_store(&donef[bt], 1, __ATOMIC_RELAXED,
                           __HIP_MEMORY_SCOPE_AGENT);
    }
    if (fid == 0) {
        if (tid < 64) {
            int v;
            unsigned long long pend;
            do {
                __builtin_amdgcn_s_sleep(2);
                v = (tid < 8)
                    ? __hip_atomic_load(&donef[tid], __ATOMIC_RELAXED,
                                        __HIP_MEMORY_SCOPE_AGENT)
                    : 1;
                pend = __ballot(v == 0);
            } while (pend != 0ull);
        }
        __syncthreads();
        if (tid == 0) {
            float total = 0.0f, cnt = 0.0f;
            for (int t = 0; t < TT; ++t) {
                float sn = __hip_atomic_load(&stepNll[t], __ATOMIC_RELAXED,
                                             __HIP_MEMORY_SCOPE_AGENT);
                float so = __hip_atomic_load(&stepObs[t], __ATOMIC_RELAXED,
                                             __HIP_MEMORY_SCOPE_AGENT);
                float sl = (so > 0.0f) ? (sn / fmaxf(so, 1.0f)) : 0.0f;
                total += sl;
                cnt += (so > 0.0f) ? 1.0f : 0.0f;
            }
            out[0] = (cnt > 0.0f) ? (total / cnt) : total;
        }
    }
}

// ---------------------------------------------------------------------------
extern "C" void kernel_launch(void* const* d_in, const int* in_sizes, int n_in,
                              void* d_out, int out_size, void* d_ws, size_t ws_size,
                              hipStream_t stream) {
    const float* target       = (const float*)d_in[0];
    const float* covariates   = (const float*)d_in[1];
    const void*  maskraw      = d_in[2];
    const int*   idx          = (const int*)d_in[3];
    const float* emb_table    = (const float*)d_in[4];
    const float* fc_w         = (const float*)d_in[5];
    const float* fc_b         = (const float*)d_in[6];
    const float* noise        = (const float*)d_in[7];
    const float* Wih0 = (const float*)d_in[8];
    const float* Whh0 = (const float*)d_in[9];
    const float* bih0 = (const float*)d_in[10];
    const float* bhh0 = (const float*)d_in[11];
    const float* Wih1 = (const float*)d_in[12];
    const float* Whh1 = (const float*)d_in[13];
    const float* bih1 = (const float*)d_in[14];
    const float* bhh1 = (const float*)d_in[15];
    const float* Wih2 = (const float*)d_in[16];
    const float* Whh2 = (const float*)d_in[17];
    const float* bih2 = (const float*)d_in[18];
    const float* bhh2 = (const float*)d_in[19];
    (void)in_sizes; (void)n_in; (void)ws_size;

    const size_t PLANE = (size_t)BB * HIDN;
    const size_t NW0 = (size_t)G4 * K0TOT;
    const size_t NW1 = (size_t)G4 * K12TOT;

    _Float16* p = (_Float16*)d_ws;
    _Float16* W0h = p; p += NW0;
    _Float16* W0l = p; p += NW0;
    _Float16* W1h = p; p += NW1;
    _Float16* W1l = p; p += NW1;
    _Float16* W2h = p; p += NW1;
    _Float16* W2l = p; p += NW1;
    _Float16* Hh  = p; p += 6 * PLANE;
    _Float16* Hl  = p; p += 6 * PLANE;
    _Float16* xdh = p; p += (size_t)BB * XLD;
    _Float16* xdl = p; p += (size_t)BB * XLD;
    float* fp = (float*)p;
    float* biasI   = fp; fp += 3 * G4;
    float* C       = fp; fp += 3 * PLANE;
    float* params  = fp; fp += 2 * BB;
    float* stepNll = fp; fp += TT;
    float* stepObs = fp; fp += TT;
    int* ip = (int*)fp;
    int* flags    = ip;      ip += 8 * 32;
    int* donef    = ip;      ip += 8;
    int* maskmode = ip;

    float* out = (float*)d_out; (void)out_size;

    pack_weights_split<<<1024, 256, 0, stream>>>(
        Wih0, Whh0, Wih1, Whh1, Wih2, Whh2,
        bih0, bhh0, bih1, bhh1, bih2, bhh2,
        W0h, W0l, W1h, W1l, W2h, W2l, biasI);
    init_state<<<1024, 256, 0, stream>>>(
        covariates, idx, emb_table, (const int*)maskraw,
        Hh, Hl, C, xdh, xdl, params, stepNll, stepObs,
        flags, donef, maskmode);

    deepar_persist<<<256, 512, 0, stream>>>(
        W0h, W0l, W1h, W1l, W2h, W2l, biasI,
        Hh, Hl, C, xdh, xdl, params, stepNll, stepObs,
        flags, donef, maskmode,
        target, covariates, maskraw, noise, fc_w, fc_b, out);
}